// Round 9
// baseline (994.386 us; speedup 1.0000x reference)
//
#include <hip/hip_runtime.h>
#include <hip/hip_bf16.h>
#include <math.h>

constexpr int DIM = 128;
constexpr int NC = 1024;
constexpr int NS = 4;
constexpr int NVEC = 16 * 8192;
constexpr size_t QSIZE = (size_t)NVEC * DIM;
constexpr int BM = 32;             // vectors per block
constexpr int CAP = 32;            // candidate slots per vector (u64 packed)
constexpr float MARGIN = 0.125f;   // >= 2 * worst-case bf16 score error (~0.044)
constexpr int RS = DIM + 1;        // 129: padded LDS residual row stride (floats)
constexpr int GSZ = 8 * 64 * 8;    // 4096 bf16 per swizzled 32-code group

typedef short bf16x8 __attribute__((ext_vector_type(8)));
typedef float f32x16 __attribute__((ext_vector_type(16)));

__device__ __forceinline__ short f2bf(float f) {
    __hip_bfloat16 h = __float2bfloat16(f);
    union { __hip_bfloat16 h; short s; } u;
    u.h = h;
    return u.s;
}

// Branchless RNE f32->bf16 (== f2bf for all finite values).
__device__ __forceinline__ short f2bf_fast(float f) {
    unsigned u = __float_as_uint(f);
    unsigned r = (u + 0x7FFFu + ((u >> 16) & 1u)) >> 16;
    return (short)r;
}

// Order-preserving float->uint map (strict order isomorphism on finite floats).
__device__ __forceinline__ unsigned fmap(float f) {
    unsigned u = __float_as_uint(f);
    return (u & 0x80000000u) ? ~u : (u | 0x80000000u);
}
__device__ __forceinline__ float funmap(unsigned k) {
    unsigned u = (k & 0x80000000u) ? (k & 0x7FFFFFFFu) : ~k;
    return __uint_as_float(u);
}

// numpy pairwise sum of squares for exactly 128 elements (8 stride-8 accums,
// tree combine, squares rounded separately).
template <typename PTR>
__device__ __forceinline__ float np_pairwise_sq128(PTR v) {
#pragma clang fp contract(off)
    float r[8];
#pragma unroll
    for (int j = 0; j < 8; ++j) { float sq = v[j] * v[j]; r[j] = sq; }
#pragma unroll
    for (int i = 8; i < DIM; i += 8) {
#pragma unroll
        for (int j = 0; j < 8; ++j) { float sq = v[i + j] * v[i + j]; r[j] = r[j] + sq; }
    }
    return ((r[0] + r[1]) + (r[2] + r[3])) + ((r[4] + r[5]) + (r[6] + r[7]));
}

// Exact numpy-recipe distance: sequential fmaf chain over d ascending,
// float4 loads (components consumed in order -> same bits as scalar).
__device__ __forceinline__ float exact_dist(const float* __restrict__ rv,
                                            const float* __restrict__ cp,
                                            float rn, float cn) {
    float a0 = 0.f;
#pragma unroll
    for (int d = 0; d < DIM; d += 4) {
        float4 q = *(const float4*)(cp + d);
        a0 = __builtin_fmaf(rv[d], q.x, a0);
        a0 = __builtin_fmaf(rv[d + 1], q.y, a0);
        a0 = __builtin_fmaf(rv[d + 2], q.z, a0);
        a0 = __builtin_fmaf(rv[d + 3], q.w, a0);
    }
    return (rn + cn) - 2.0f * a0;
}

// Prologue A: exact fp32 code norms (numpy recipe).
__global__ __launch_bounds__(256) void rvq_norms(
        const float* __restrict__ cb, float* __restrict__ cnorm) {
    int row = blockIdx.x * 256 + threadIdx.x;
    if (row >= NS * NC) return;
    cnorm[row] = np_pairwise_sq128(cb + (size_t)row * DIM);
}

// Prologue B: swizzle codebook into fragment-linear bf16 layout.
// swz[s][g][ks][l][j] = f2bf(cb[s][g*32 + (l&31)][ks*16 + (l>>5)*8 + j])
__global__ __launch_bounds__(256) void rvq_swizzle(
        const float* __restrict__ cb, short* __restrict__ swz) {
    int bg = blockIdx.x;            // (s*32 + g), 128 blocks
    const float* src = cb + (size_t)bg * 32 * DIM;
    short* dst = swz + (size_t)bg * GSZ;
    int t = threadIdx.x;
#pragma unroll
    for (int i = 0; i < 2; ++i) {
        int o = t * 16 + i * 8;     // bf16 offset in group, multiple of 8
        int ks = o >> 9;
        int l = (o >> 3) & 63;
        const float* p = src + (l & 31) * DIM + ks * 16 + (l >> 5) * 8;
        bf16x8 v;
#pragma unroll
        for (int j = 0; j < 8; ++j) v[j] = f2bf(p[j]);
        *(bf16x8*)(dst + o) = v;
    }
}

__global__ __launch_bounds__(256, 4) void rvq_main(
        const float* __restrict__ x,
        const float* __restrict__ cb,       // fp32 codebooks (exact path)
        const short* __restrict__ swz,      // swizzled bf16 codebooks (MFMA path)
        const float* __restrict__ cnorm_ws, // exact code norms
        float* __restrict__ out) {
    __shared__ float s_res[BM * RS];              // 16.5KB fp32 residuals, +1 pad
    __shared__ float s_cnorm[NC];                 // 4KB
    __shared__ unsigned s_vmin[BM];               // shared running approx min
    __shared__ unsigned long long s_cand[BM * CAP]; // 8KB (score<<32 | code)
    __shared__ unsigned long long s_best[BM];     // packed (exact dist, idx) min
    __shared__ float s_rn[BM];
    __shared__ int s_cnt[BM];
    __shared__ int s_ovf[BM];
    __shared__ int s_idx[BM];
    __shared__ int s_ovlist[BM];
    __shared__ int s_ovn;

    const int tid = threadIdx.x;
    const int w = tid >> 6;      // wave 0..3: owns codes [w*256, w*256+256)
    const int l = tid & 63;
    const int l31 = l & 31;      // this lane's vector slot
    const int h = l >> 5;
    const int Q = w * 256;
    const int blockbase = blockIdx.x * BM;

    // ---- init: residual = x ----
    for (int i4 = tid; i4 < BM * DIM / 4; i4 += 256) {
        int vec = i4 >> 5, d4 = (i4 & 31) * 4;
        float4 t = *(const float4*)(x + (size_t)(blockbase + vec) * DIM + d4);
        float* rp = &s_res[vec * RS + d4];
        rp[0] = t.x; rp[1] = t.y; rp[2] = t.z; rp[3] = t.w;
    }

#pragma unroll 1
    for (int s = 0; s < NS; ++s) {
        // ---- stage setup ----
        for (int i = tid; i < NC; i += 256) s_cnorm[i] = cnorm_ws[s * NC + i];
        if (tid < BM) {
            s_cnt[tid] = 0; s_ovf[tid] = 0; s_vmin[tid] = 0xFFFFFFFFu;
            s_best[tid] = ~0ull;
        }
        if (tid == 0) s_ovn = 0;
        __syncthreads();   // also covers: previous stage's residual update done

        // Per-vector exact residual norm (numpy recipe), once per stage.
        if (tid < BM) s_rn[tid] = np_pairwise_sq128(&s_res[tid * RS]);

        // B fragments from LDS residual; same assumed k-map as the swizzled A
        // layout -> k-layout errors cancel (round-3-verified).
        bf16x8 breg[8];
        {
            const float* p = &s_res[l31 * RS + h * 8];
#pragma unroll
            for (int ks = 0; ks < 8; ++ks) {
                bf16x8 b;
#pragma unroll
                for (int j = 0; j < 8; ++j) b[j] = f2bf_fast(p[ks * 16 + j]);
                breg[ks] = b;
            }
        }

        const short* swz_s = swz + (size_t)s * 32 * GSZ;

        // ---- single sweep: shared running min + margin-append ----
        // Stale thresholds only ADMIT extras (superset); the post-sweep filter
        // against the final vmin restores the deterministic candidate set.
        // NOTE: cnorm for accumulator slot r is s_cnorm[code(r)] (same index
        // as the code id); reading it scalar per use (half-wave-uniform LDS
        // broadcast) keeps peak register pressure ~100 total -> no spill at
        // the 128-reg/wave budget of __launch_bounds__(256,4).
#pragma unroll 2
        for (int sub = 0; sub < 8; ++sub) {
            const int cbase = Q + sub * 32;
            const short* ap = swz_s + (size_t)(w * 8 + sub) * GSZ;
            f32x16 acc;
#pragma unroll
            for (int j = 0; j < 16; ++j) acc[j] = 0.f;
#pragma unroll
            for (int ks = 0; ks < 8; ++ks) {
                bf16x8 a = *(const bf16x8*)(ap + ks * 512 + l * 8);
                acc = __builtin_amdgcn_mfma_f32_32x32x16_bf16(a, breg[ks], acc, 0, 0, 0);
            }
            // pass A: tree min of the 16 scores (values consumed immediately)
            float lmin = INFINITY;
#pragma unroll
            for (int r = 0; r < 16; ++r) {
                int code = cbase + (r & 3) + 8 * (r >> 2) + 4 * h;
                float scr = fmaf(acc[r], -2.f, s_cnorm[code]);
                lmin = fminf(lmin, scr);
            }
            unsigned mymap = fmap(lmin);
            unsigned cur = atomicMin(&s_vmin[l31], mymap);  // returns old
            unsigned tU = cur < mymap ? cur : mymap;
            float thr = funmap(tU) + MARGIN;
            // pass B: recompute scores, margin-append
#pragma unroll
            for (int r = 0; r < 16; ++r) {
                int code = cbase + (r & 3) + 8 * (r >> 2) + 4 * h;
                float scr = fmaf(acc[r], -2.f, s_cnorm[code]);
                if (scr <= thr) {
                    int o = atomicAdd(&s_cnt[l31], 1);
                    if (o < CAP)
                        s_cand[l31 * CAP + o] =
                            ((unsigned long long)fmap(scr) << 32) | (unsigned)code;
                    else s_ovf[l31] = 1;
                }
            }
        }
        __syncthreads();

        // ---- filter against FINAL vmin (deterministic set), m==1 shortcut ----
        if (tid < BM && !s_ovf[tid]) {
            int n = s_cnt[tid];            // <= CAP if no overflow
            unsigned thrF = fmap(funmap(s_vmin[tid]) + MARGIN);
            int m = 0;
            unsigned long long keep = 0;
            for (int j = 0; j < n; ++j) {
                unsigned long long pk = s_cand[tid * CAP + j];
                if ((unsigned)(pk >> 32) <= thrF) {
                    s_cand[tid * CAP + m] = pk; keep = pk; ++m;
                }
            }
            s_cnt[tid] = m;
            if (m == 1) s_idx[tid] = (int)(unsigned)(keep & 0xFFFFFFFFull);
        }
        __syncthreads();

        // ---- exact fp32 re-rank, 8-way candidate-parallel (4 waves x 2 halves)
        // u64 atomicMin on (fmap(dist)<<32|code) == lexicographic (dist, idx)
        // min == numpy first-occurrence argmin.
        {
            int vec = l31;
            if (!s_ovf[vec]) {
                int m = s_cnt[vec];
                if (m >= 2) {
                    const float* rv = &s_res[vec * RS];
                    float rn = s_rn[vec];
                    for (int k = w * 2 + h; k < m; k += 8) {
                        int c = (int)(unsigned)(s_cand[vec * CAP + k] & 0xFFFFFFFFull);
                        float dist = exact_dist(rv, cb + ((size_t)s * NC + c) * DIM,
                                                rn, s_cnorm[c]);
                        atomicMin(&s_best[vec],
                                  ((unsigned long long)fmap(dist) << 32) | (unsigned)c);
                    }
                }
            }
        }
        __syncthreads();
        if (tid < BM && !s_ovf[tid] && s_cnt[tid] > 1)
            s_idx[tid] = (int)(unsigned)(s_best[tid] & 0xFFFFFFFFull);
        if (tid < BM && s_ovf[tid]) {
            int p = atomicAdd(&s_ovn, 1);
            s_ovlist[p] = tid;
        }
        __syncthreads();
        // ultra-rare overflow: wave-parallel exact scan over all 1024 codes
        for (int o = w; o < s_ovn; o += 4) {
            int vec = s_ovlist[o];
            const float* rv = &s_res[vec * RS];
            float rn = s_rn[vec];
            float best = INFINITY; int bidx = 0;
            for (int k = 0; k < 16; ++k) {
                int c = k * 64 + l;
                float dist = exact_dist(rv, cb + ((size_t)s * NC + c) * DIM,
                                        rn, s_cnorm[c]);
                if (dist < best) { best = dist; bidx = c; }
            }
#pragma unroll
            for (int off = 32; off >= 1; off >>= 1) {
                float ob = __shfl_xor(best, off, 64);
                int oi = __shfl_xor(bidx, off, 64);
                if (ob < best || (ob == best && oi < bidx)) { best = ob; bidx = oi; }
            }
            if (l == 0) s_idx[vec] = bidx;
        }
        __syncthreads();

        // ---- residual update in LDS (exact fp32) / final q write ----
        if (s < NS - 1) {
            for (int i4 = tid; i4 < BM * DIM / 4; i4 += 256) {
                int vec = i4 >> 5, d4 = (i4 & 31) * 4;
                int c = s_idx[vec];
                float4 cc = *(const float4*)(cb + ((size_t)s * NC + c) * DIM + d4);
                float* rp = &s_res[vec * RS + d4];
                rp[0] = rp[0] - cc.x; rp[1] = rp[1] - cc.y;
                rp[2] = rp[2] - cc.z; rp[3] = rp[3] - cc.w;
            }
        } else {  // q = x - (r - chosen)
            for (int i4 = tid; i4 < BM * DIM / 4; i4 += 256) {
                int vec = i4 >> 5, d4 = (i4 & 31) * 4;
                int c = s_idx[vec];
                float4 cc = *(const float4*)(cb + ((size_t)s * NC + c) * DIM + d4);
                float4 xx = *(const float4*)(x + (size_t)(blockbase + vec) * DIM + d4);
                const float* rp = &s_res[vec * RS + d4];
                float4 oo;
                oo.x = xx.x - (rp[0] - cc.x); oo.y = xx.y - (rp[1] - cc.y);
                oo.z = xx.z - (rp[2] - cc.z); oo.w = xx.w - (rp[3] - cc.w);
                *(float4*)(out + (size_t)(blockbase + vec) * DIM + d4) = oo;
            }
        }
        if (tid < BM)
            out[QSIZE + (size_t)s * NVEC + blockbase + tid] = (float)s_idx[tid];
        __syncthreads();
    }
}

extern "C" void kernel_launch(void* const* d_in, const int* in_sizes, int n_in,
                              void* d_out, int out_size, void* d_ws, size_t ws_size,
                              hipStream_t stream) {
    const float* x  = (const float*)d_in[0];   // [16, 8192, 128] fp32
    const float* cb = (const float*)d_in[1];   // [4, 1024, 128] fp32
    short* swz = (short*)d_ws;                                     // 1 MB
    float* cnorm = (float*)((char*)d_ws + (size_t)NS * NC * DIM * sizeof(short));
    float* out = (float*)d_out;

    rvq_norms<<<(NS * NC + 255) / 256, 256, 0, stream>>>(cb, cnorm);
    rvq_swizzle<<<NS * 32, 256, 0, stream>>>(cb, swz);
    rvq_main<<<NVEC / BM, 256, 0, stream>>>(x, cb, swz, cnorm, out);
}

// Round 10
// 762.934 us; speedup vs baseline: 1.3034x; 1.3034x over previous
//
#include <hip/hip_runtime.h>
#include <hip/hip_bf16.h>
#include <math.h>

constexpr int DIM = 128;
constexpr int NC = 1024;
constexpr int NS = 4;
constexpr int NVEC = 16 * 8192;
constexpr size_t QSIZE = (size_t)NVEC * DIM;
constexpr int BM = 32;             // vectors per block
constexpr int CAP = 32;            // candidate slots per vector (u64 packed)
constexpr float MARGIN = 0.125f;   // >= 2 * worst-case bf16 score error (~0.044)
constexpr int RS = DIM + 1;        // 129: padded LDS residual row stride (floats)
constexpr int GSZ = 8 * 64 * 8;    // 4096 bf16 per swizzled 32-code group

typedef short bf16x8 __attribute__((ext_vector_type(8)));
typedef float f32x16 __attribute__((ext_vector_type(16)));

__device__ __forceinline__ short f2bf(float f) {
    __hip_bfloat16 h = __float2bfloat16(f);
    union { __hip_bfloat16 h; short s; } u;
    u.h = h;
    return u.s;
}

// Branchless RNE f32->bf16 (== f2bf for all finite values).
__device__ __forceinline__ short f2bf_fast(float f) {
    unsigned u = __float_as_uint(f);
    unsigned r = (u + 0x7FFFu + ((u >> 16) & 1u)) >> 16;
    return (short)r;
}

// Order-preserving float->uint map (strict order isomorphism on finite floats).
__device__ __forceinline__ unsigned fmap(float f) {
    unsigned u = __float_as_uint(f);
    return (u & 0x80000000u) ? ~u : (u | 0x80000000u);
}
__device__ __forceinline__ float funmap(unsigned k) {
    unsigned u = (k & 0x80000000u) ? (k & 0x7FFFFFFFu) : ~k;
    return __uint_as_float(u);
}

// numpy pairwise sum of squares for exactly 128 elements (8 stride-8 accums,
// tree combine, squares rounded separately).
template <typename PTR>
__device__ __forceinline__ float np_pairwise_sq128(PTR v) {
#pragma clang fp contract(off)
    float r[8];
#pragma unroll
    for (int j = 0; j < 8; ++j) { float sq = v[j] * v[j]; r[j] = sq; }
#pragma unroll
    for (int i = 8; i < DIM; i += 8) {
#pragma unroll
        for (int j = 0; j < 8; ++j) { float sq = v[i + j] * v[i + j]; r[j] = r[j] + sq; }
    }
    return ((r[0] + r[1]) + (r[2] + r[3])) + ((r[4] + r[5]) + (r[6] + r[7]));
}

// Exact numpy-recipe distance: sequential fmaf chain over d ascending,
// float4 loads (components consumed in order -> same bits as scalar).
__device__ __forceinline__ float exact_dist(const float* __restrict__ rv,
                                            const float* __restrict__ cp,
                                            float rn, float cn) {
    float a0 = 0.f;
#pragma unroll
    for (int d = 0; d < DIM; d += 4) {
        float4 q = *(const float4*)(cp + d);
        a0 = __builtin_fmaf(rv[d], q.x, a0);
        a0 = __builtin_fmaf(rv[d + 1], q.y, a0);
        a0 = __builtin_fmaf(rv[d + 2], q.z, a0);
        a0 = __builtin_fmaf(rv[d + 3], q.w, a0);
    }
    return (rn + cn) - 2.0f * a0;
}

// Prologue A: exact fp32 code norms (numpy recipe).
__global__ __launch_bounds__(256) void rvq_norms(
        const float* __restrict__ cb, float* __restrict__ cnorm) {
    int row = blockIdx.x * 256 + threadIdx.x;
    if (row >= NS * NC) return;
    cnorm[row] = np_pairwise_sq128(cb + (size_t)row * DIM);
}

// Prologue B: swizzle codebook into fragment-linear bf16 layout.
// swz[s][g][ks][l][j] = f2bf(cb[s][g*32 + (l&31)][ks*16 + (l>>5)*8 + j])
__global__ __launch_bounds__(256) void rvq_swizzle(
        const float* __restrict__ cb, short* __restrict__ swz) {
    int bg = blockIdx.x;            // (s*32 + g), 128 blocks
    const float* src = cb + (size_t)bg * 32 * DIM;
    short* dst = swz + (size_t)bg * GSZ;
    int t = threadIdx.x;
#pragma unroll
    for (int i = 0; i < 2; ++i) {
        int o = t * 16 + i * 8;     // bf16 offset in group, multiple of 8
        int ks = o >> 9;
        int l = (o >> 3) & 63;
        const float* p = src + (l & 31) * DIM + ks * 16 + (l >> 5) * 8;
        bf16x8 v;
#pragma unroll
        for (int j = 0; j < 8; ++j) v[j] = f2bf(p[j]);
        *(bf16x8*)(dst + o) = v;
    }
}

// NOTE: no min-waves bound. (256,4) capped the unified VGPR/AGPR file at 64
// arch VGPRs and forced a ~550MB/dispatch scratch round-trip (r8/r9 PMC:
// WRITE_SIZE 623MB vs ~69MB real). Natural demand is ~100-130 regs.
__global__ __launch_bounds__(256) void rvq_main(
        const float* __restrict__ x,
        const float* __restrict__ cb,       // fp32 codebooks (exact path)
        const short* __restrict__ swz,      // swizzled bf16 codebooks (MFMA path)
        const float* __restrict__ cnorm_ws, // exact code norms
        float* __restrict__ out) {
    __shared__ float s_res[BM * RS];              // 16.5KB fp32 residuals, +1 pad
    __shared__ float s_cnorm[NC];                 // 4KB
    __shared__ unsigned s_vmin[BM];               // shared running approx min
    __shared__ unsigned long long s_cand[BM * CAP]; // 8KB (score<<32 | code)
    __shared__ unsigned long long s_best[BM];     // packed (exact dist, idx) min
    __shared__ float s_rn[BM];
    __shared__ int s_cnt[BM];
    __shared__ int s_ovf[BM];
    __shared__ int s_idx[BM];
    __shared__ int s_ovlist[BM];
    __shared__ int s_ovn;

    const int tid = threadIdx.x;
    const int w = tid >> 6;      // wave 0..3: owns codes [w*256, w*256+256)
    const int l = tid & 63;
    const int l31 = l & 31;      // this lane's vector slot
    const int h = l >> 5;
    const int Q = w * 256;
    const int blockbase = blockIdx.x * BM;

    // ---- init: residual = x ----
    for (int i4 = tid; i4 < BM * DIM / 4; i4 += 256) {
        int vec = i4 >> 5, d4 = (i4 & 31) * 4;
        float4 t = *(const float4*)(x + (size_t)(blockbase + vec) * DIM + d4);
        float* rp = &s_res[vec * RS + d4];
        rp[0] = t.x; rp[1] = t.y; rp[2] = t.z; rp[3] = t.w;
    }

#pragma unroll 1
    for (int s = 0; s < NS; ++s) {
        // ---- stage setup ----
        for (int i = tid; i < NC; i += 256) s_cnorm[i] = cnorm_ws[s * NC + i];
        if (tid < BM) {
            s_cnt[tid] = 0; s_ovf[tid] = 0; s_vmin[tid] = 0xFFFFFFFFu;
            s_best[tid] = ~0ull;
        }
        if (tid == 0) s_ovn = 0;
        __syncthreads();   // also covers: previous stage's residual update done

        // Per-vector exact residual norm (numpy recipe), once per stage.
        if (tid < BM) s_rn[tid] = np_pairwise_sq128(&s_res[tid * RS]);

        // B fragments from LDS residual; same assumed k-map as the swizzled A
        // layout -> k-layout errors cancel (round-3-verified).
        bf16x8 breg[8];
        {
            const float* p = &s_res[l31 * RS + h * 8];
#pragma unroll
            for (int ks = 0; ks < 8; ++ks) {
                bf16x8 b;
#pragma unroll
                for (int j = 0; j < 8; ++j) b[j] = f2bf_fast(p[ks * 16 + j]);
                breg[ks] = b;
            }
        }

        const short* swz_s = swz + (size_t)s * 32 * GSZ;

        // ---- single sweep: shared running min + margin-append ----
        // Stale thresholds only ADMIT extras (superset); the post-sweep filter
        // against the final vmin restores the deterministic candidate set.
#pragma unroll 2
        for (int sub = 0; sub < 8; ++sub) {
            const int cbase = Q + sub * 32;
            const short* ap = swz_s + (size_t)(w * 8 + sub) * GSZ;
            f32x16 acc;
#pragma unroll
            for (int j = 0; j < 16; ++j) acc[j] = 0.f;
#pragma unroll
            for (int ks = 0; ks < 8; ++ks) {
                bf16x8 a = *(const bf16x8*)(ap + ks * 512 + l * 8);
                acc = __builtin_amdgcn_mfma_f32_32x32x16_bf16(a, breg[ks], acc, 0, 0, 0);
            }
            // pass A: tree min of the 16 scores (values consumed immediately)
            float lmin = INFINITY;
#pragma unroll
            for (int r = 0; r < 16; ++r) {
                int code = cbase + (r & 3) + 8 * (r >> 2) + 4 * h;
                float scr = fmaf(acc[r], -2.f, s_cnorm[code]);
                lmin = fminf(lmin, scr);
            }
            unsigned mymap = fmap(lmin);
            unsigned cur = atomicMin(&s_vmin[l31], mymap);  // returns old
            unsigned tU = cur < mymap ? cur : mymap;
            float thr = funmap(tU) + MARGIN;
            // pass B: recompute scores, margin-append
#pragma unroll
            for (int r = 0; r < 16; ++r) {
                int code = cbase + (r & 3) + 8 * (r >> 2) + 4 * h;
                float scr = fmaf(acc[r], -2.f, s_cnorm[code]);
                if (scr <= thr) {
                    int o = atomicAdd(&s_cnt[l31], 1);
                    if (o < CAP)
                        s_cand[l31 * CAP + o] =
                            ((unsigned long long)fmap(scr) << 32) | (unsigned)code;
                    else s_ovf[l31] = 1;
                }
            }
        }
        __syncthreads();

        // ---- filter against FINAL vmin (deterministic set), m==1 shortcut ----
        if (tid < BM && !s_ovf[tid]) {
            int n = s_cnt[tid];            // <= CAP if no overflow
            unsigned thrF = fmap(funmap(s_vmin[tid]) + MARGIN);
            int m = 0;
            unsigned long long keep = 0;
            for (int j = 0; j < n; ++j) {
                unsigned long long pk = s_cand[tid * CAP + j];
                if ((unsigned)(pk >> 32) <= thrF) {
                    s_cand[tid * CAP + m] = pk; keep = pk; ++m;
                }
            }
            s_cnt[tid] = m;
            if (m == 1) s_idx[tid] = (int)(unsigned)(keep & 0xFFFFFFFFull);
        }
        __syncthreads();

        // ---- exact fp32 re-rank, 8-way candidate-parallel (4 waves x 2 halves)
        // u64 atomicMin on (fmap(dist)<<32|code) == lexicographic (dist, idx)
        // min == numpy first-occurrence argmin.
        {
            int vec = l31;
            if (!s_ovf[vec]) {
                int m = s_cnt[vec];
                if (m >= 2) {
                    const float* rv = &s_res[vec * RS];
                    float rn = s_rn[vec];
                    for (int k = w * 2 + h; k < m; k += 8) {
                        int c = (int)(unsigned)(s_cand[vec * CAP + k] & 0xFFFFFFFFull);
                        float dist = exact_dist(rv, cb + ((size_t)s * NC + c) * DIM,
                                                rn, s_cnorm[c]);
                        atomicMin(&s_best[vec],
                                  ((unsigned long long)fmap(dist) << 32) | (unsigned)c);
                    }
                }
            }
        }
        __syncthreads();
        if (tid < BM && !s_ovf[tid] && s_cnt[tid] > 1)
            s_idx[tid] = (int)(unsigned)(s_best[tid] & 0xFFFFFFFFull);
        if (tid < BM && s_ovf[tid]) {
            int p = atomicAdd(&s_ovn, 1);
            s_ovlist[p] = tid;
        }
        __syncthreads();
        // ultra-rare overflow: wave-parallel exact scan over all 1024 codes
        for (int o = w; o < s_ovn; o += 4) {
            int vec = s_ovlist[o];
            const float* rv = &s_res[vec * RS];
            float rn = s_rn[vec];
            float best = INFINITY; int bidx = 0;
            for (int k = 0; k < 16; ++k) {
                int c = k * 64 + l;
                float dist = exact_dist(rv, cb + ((size_t)s * NC + c) * DIM,
                                        rn, s_cnorm[c]);
                if (dist < best) { best = dist; bidx = c; }
            }
#pragma unroll
            for (int off = 32; off >= 1; off >>= 1) {
                float ob = __shfl_xor(best, off, 64);
                int oi = __shfl_xor(bidx, off, 64);
                if (ob < best || (ob == best && oi < bidx)) { best = ob; bidx = oi; }
            }
            if (l == 0) s_idx[vec] = bidx;
        }
        __syncthreads();

        // ---- residual update in LDS (exact fp32) / final q write ----
        if (s < NS - 1) {
            for (int i4 = tid; i4 < BM * DIM / 4; i4 += 256) {
                int vec = i4 >> 5, d4 = (i4 & 31) * 4;
                int c = s_idx[vec];
                float4 cc = *(const float4*)(cb + ((size_t)s * NC + c) * DIM + d4);
                float* rp = &s_res[vec * RS + d4];
                rp[0] = rp[0] - cc.x; rp[1] = rp[1] - cc.y;
                rp[2] = rp[2] - cc.z; rp[3] = rp[3] - cc.w;
            }
        } else {  // q = x - (r - chosen)
            for (int i4 = tid; i4 < BM * DIM / 4; i4 += 256) {
                int vec = i4 >> 5, d4 = (i4 & 31) * 4;
                int c = s_idx[vec];
                float4 cc = *(const float4*)(cb + ((size_t)s * NC + c) * DIM + d4);
                float4 xx = *(const float4*)(x + (size_t)(blockbase + vec) * DIM + d4);
                const float* rp = &s_res[vec * RS + d4];
                float4 oo;
                oo.x = xx.x - (rp[0] - cc.x); oo.y = xx.y - (rp[1] - cc.y);
                oo.z = xx.z - (rp[2] - cc.z); oo.w = xx.w - (rp[3] - cc.w);
                *(float4*)(out + (size_t)(blockbase + vec) * DIM + d4) = oo;
            }
        }
        if (tid < BM)
            out[QSIZE + (size_t)s * NVEC + blockbase + tid] = (float)s_idx[tid];
        __syncthreads();
    }
}

extern "C" void kernel_launch(void* const* d_in, const int* in_sizes, int n_in,
                              void* d_out, int out_size, void* d_ws, size_t ws_size,
                              hipStream_t stream) {
    const float* x  = (const float*)d_in[0];   // [16, 8192, 128] fp32
    const float* cb = (const float*)d_in[1];   // [4, 1024, 128] fp32
    short* swz = (short*)d_ws;                                     // 1 MB
    float* cnorm = (float*)((char*)d_ws + (size_t)NS * NC * DIM * sizeof(short));
    float* out = (float*)d_out;

    rvq_norms<<<(NS * NC + 255) / 256, 256, 0, stream>>>(cb, cnorm);
    rvq_swizzle<<<NS * 32, 256, 0, stream>>>(cb, swz);
    rvq_main<<<NVEC / BM, 256, 0, stream>>>(x, cb, swz, cnorm, out);
}